// Round 5
// baseline (294.151 us; speedup 1.0000x reference)
//
#include <hip/hip_runtime.h>

#define NL2E (-1.4426950408889634f)

__device__ __forceinline__ float rl(float v, int lane) {
    return __int_as_float(__builtin_amdgcn_readlane(__float_as_int(v), lane));
}

__global__ __launch_bounds__(64) void leaf_integ_kernel(
    const float* __restrict__ S_conv, const float* __restrict__ up_mu_Z,
    const float* __restrict__ noise, const float* __restrict__ W_sub,
    const float* __restrict__ theta_syn, const float* __restrict__ theta_spike,
    const float* __restrict__ W_spike, const float* __restrict__ tau_hist,
    const float* __restrict__ K_hist, const float* __restrict__ delta_hist,
    float* __restrict__ out)
{
    const int SUB = 1024;
    int bid = blockIdx.x;
    int s = ((bid & 7) << 7) + (bid >> 3);   // XCD-locality swizzle
    int l = threadIdx.x;
    bool hi = (l >= 32);          // hi half processes odd steps of each pair
    int pidx = hi ? 1 : 0;
    int rimR = l >> 1;            // iter at which this lane's accumulator resets
    int rimC = l & 31;            // iter at which this lane's half captures
    int step2 = 2 * rimC + pidx;  // capture-layout step offset within a block

    __shared__ float lds_rev[128];

    float thsyn = theta_syn[s];
    float thspk = theta_spike[s];
    float wsub  = W_sub[s];
    float wspk  = W_spike[s];
    float delta = delta_hist[s];

    // history kernel, pre-scaled by -log2(e); kern[0] == 0 identically
    float tt = fmaxf((float)l - delta, 0.0f);
    float kern = 0.0f;
    #pragma unroll
    for (int b = 0; b < 4; ++b) {
        float rtau = __expf(-tau_hist[b]);
        float ttau = tt * rtau;
        kern += ttau * __expf(-ttau) * K_hist[s * 4 + b];
    }
    float kvs = NL2E * kern;
    lds_rev[63 - l]  = kvs;
    lds_rev[127 - l] = kvs;
    __syncthreads();

    // near-correction taps (wave-uniform, packed per half):
    // z(pair i) -> ab(pair i+1): lo gets kern[1],kern[0](=0); hi gets kern[2],kern[1]
    float k1v = rl(kvs, 1), k2v = rl(kvs, 2);
    float kca = hi ? k2v : k1v;    // x z0
    float kcb = hi ? k1v : 0.0f;   // x z1

    const float* krow = &lds_rev[64 - l];  // krow[j] = scaled kern[(l-1-j)&63]

    float thsynS = NL2E * thsyn;
    float c1 = NL2E * 0.5f * wspk;

    // prologue loads
    float s0raw = S_conv[(size_t)l * SUB + s];
    float s1raw = S_conv[(size_t)(64 + l) * SUB + s];
    float up0   = up_mu_Z[(size_t)l * SUB + s];
    float n0    = noise[(size_t)l * SUB + s];
    float upC   = up_mu_Z[(size_t)step2 * SUB + s];  // capture-layout up, block 0

    float A    = fmaf(s0raw, NL2E, thsynS);  // lane l: accumulator for step == l (mod 64)
    float sA   = fmaf(s1raw, NL2E, thsynS);
    float preA = NL2E * (fmaf(0.5f, up0, 0.5f * thspk) + n0);

    // pipeline fill (zero z-history, so raw reads are exact here)
    float ab0 = hi ? rl(A, 1) : rl(A, 0);
    float xoP = __builtin_amdgcn_rcpf(1.0f + __builtin_amdgcn_exp2f(ab0));
    float abN = hi ? rl(A, 3) : rl(A, 2);   // pair 1; near-corr applied in iter 0
    float pbP = hi ? rl(preA, 1) : rl(preA, 0);
    float klo = krow[0];
    float khi = krow[1];

    float xcapH = 0.0f, zcapH = 0.0f;

    float* Yo = out;
    float* Zo = out + 4194304;
    float* Mo = out + 8388608;
    float* Do = out + 12582912;

    for (int B = 0; B < 64; ++B) {
        int t0 = B * 64;
        // global prefetch: s for block B+2, pre-inputs for B+1, upC for B+1
        int tP = min(t0 + 128 + l, 4095);
        int tQ = min(t0 + 64 + l, 4095);
        int tU = min(t0 + 64 + step2, 4095);
        float sB   = S_conv[(size_t)tP * SUB + s];
        float upB  = up_mu_Z[(size_t)tQ * SUB + s];
        float nB   = noise[(size_t)tQ * SUB + s];
        float upCn = up_mu_Z[(size_t)tU * SUB + s];

        #pragma unroll
        for (int i = 0; i < 32; ++i) {
            // ---- critical chain (identical to R2) ----
            float vv = fmaf(xoP, c1, pbP);
            float e2 = __builtin_amdgcn_exp2f(vv);
            float zP = __builtin_amdgcn_rcpf(1.0f + e2);
            bool cap = (rimC == i);
            xcapH = cap ? xoP : xcapH;
            zcapH = cap ? zP  : zcapH;
            float z0 = rl(zP, 0);
            float z1 = rl(zP, 32);
            abN = fmaf(kca, z0, abN);          // near corrections (on-chain)
            abN = fmaf(kcb, z1, abN);
            float e1 = __builtin_amdgcn_exp2f(abN);
            float xoN = __builtin_amdgcn_rcpf(1.0f + e1);
            // ---- off-chain ----
            float Ab = (rimR == i) ? sA : A;   // ring reset at consumption
            Ab = fmaf(klo, z0, Ab);            // scatter (taps prefetched last iter)
            A  = fmaf(khi, z1, Ab);
            // tap prefetch for next iter (LDS latency covered)
            int jl = (2 * i + 2) & 63;
            float kloN = krow[jl];
            float khiN = krow[jl + 1];
            // pre-read ab for pair i+2 (after scatter; kern[>=3] terms via A)
            int p0 = (2 * i + 4) & 63, p1 = (2 * i + 5) & 63;
            float aN = hi ? rl(A, p1) : rl(A, p0);
            // pb for pair i+1 via readlane of register (no LDS)
            float pbN = 0.0f;
            if (i < 31) pbN = hi ? rl(preA, 2 * i + 3) : rl(preA, 2 * i + 2);
            // rotate pipeline
            xoP = xoN; abN = aN; pbP = pbN; klo = kloN; khi = khiN;
        }

        // block end: direct store from capture layout (lane l holds step t0+step2)
        float down = fmaf(xcapH, wspk, thspk);
        float Yv   = xcapH * wsub;
        float mu   = 0.5f * (upC + down);
        size_t o = (size_t)(t0 + step2) * SUB + s;
        Yo[o] = Yv; Zo[o] = zcapH; Mo[o] = mu; Do[o] = down;

        // roll double-buffered inputs
        sA   = fmaf(sB, NL2E, thsynS);
        preA = NL2E * (fmaf(0.5f, upB, 0.5f * thspk) + nB);
        upC  = upCn;
        pbP  = hi ? rl(preA, 1) : rl(preA, 0);   // pb for pair 0 of next block
    }
}

extern "C" void kernel_launch(void* const* d_in, const int* in_sizes, int n_in,
                              void* d_out, int out_size, void* d_ws, size_t ws_size,
                              hipStream_t stream) {
    const float* S_conv     = (const float*)d_in[0];
    const float* up_mu_Z    = (const float*)d_in[1];
    const float* noise      = (const float*)d_in[2];
    const float* W_sub      = (const float*)d_in[3];
    const float* theta_syn  = (const float*)d_in[4];
    const float* theta_spike= (const float*)d_in[5];
    const float* W_spike    = (const float*)d_in[6];
    const float* tau_hist   = (const float*)d_in[7];
    const float* K_hist     = (const float*)d_in[8];
    const float* delta_hist = (const float*)d_in[9];
    float* out = (float*)d_out;

    leaf_integ_kernel<<<dim3(1024), dim3(64), 0, stream>>>(
        S_conv, up_mu_Z, noise, W_sub, theta_syn, theta_spike, W_spike,
        tau_hist, K_hist, delta_hist, out);
}

// Round 6
// 132.155 us; speedup vs baseline: 2.2258x; 2.2258x over previous
//
#include <hip/hip_runtime.h>

#define NL2E (-1.4426950408889634f)

__device__ __forceinline__ float rl(float v, int lane) {
    return __int_as_float(__builtin_amdgcn_readlane(__float_as_int(v), lane));
}

__global__ __launch_bounds__(64) void leaf_integ_kernel(
    const float* __restrict__ S_conv, const float* __restrict__ up_mu_Z,
    const float* __restrict__ noise, const float* __restrict__ W_sub,
    const float* __restrict__ theta_syn, const float* __restrict__ theta_spike,
    const float* __restrict__ W_spike, const float* __restrict__ tau_hist,
    const float* __restrict__ K_hist, const float* __restrict__ delta_hist,
    float* __restrict__ out)
{
    const int SUB = 1024;
    int bid = blockIdx.x;
    int s = ((bid & 7) << 7) + (bid >> 3);   // XCD-locality swizzle
    int l = threadIdx.x;
    bool hi = (l >= 32);          // hi half processes odd steps of each pair
    int pidx = hi ? 1 : 0;
    int rimR = l >> 1;            // iter at which this lane's accumulator resets
    int rimC = l & 31;            // iter at which this lane's half captures
    int step2 = 2 * rimC + pidx;  // capture-layout step offset within a block

    __shared__ float lds_rev[128];
    __shared__ float preLds[64];

    float thsyn = theta_syn[s];
    float thspk = theta_spike[s];
    float wsub  = W_sub[s];
    float wspk  = W_spike[s];
    float delta = delta_hist[s];

    // history kernel, pre-scaled by -log2(e); kern[0] == 0 identically
    float tt = fmaxf((float)l - delta, 0.0f);
    float kern = 0.0f;
    #pragma unroll
    for (int b = 0; b < 4; ++b) {
        float rtau = __expf(-tau_hist[b]);
        float ttau = tt * rtau;
        kern += ttau * __expf(-ttau) * K_hist[s * 4 + b];
    }
    float kvs = NL2E * kern;
    lds_rev[63 - l]  = kvs;
    lds_rev[127 - l] = kvs;
    __syncthreads();

    // near-correction taps (wave-uniform, packed per half):
    // z(pair i) -> ab(pair i+1): lo gets kern[1],kern[0](=0); hi gets kern[2],kern[1]
    float k1v = rl(kvs, 1), k2v = rl(kvs, 2);
    float kca = hi ? k2v : k1v;    // x z0
    float kcb = hi ? k1v : 0.0f;   // x z1

    const float* krow = &lds_rev[64 - l];  // krow[j] = scaled kern[(l-1-j)&63]

    float thsynS = NL2E * thsyn;
    float c1 = NL2E * 0.5f * wspk;

    // prologue loads
    float s0raw = S_conv[(size_t)l * SUB + s];
    float s1raw = S_conv[(size_t)(64 + l) * SUB + s];
    float up0   = up_mu_Z[(size_t)l * SUB + s];
    float n0    = noise[(size_t)l * SUB + s];
    float upC   = up_mu_Z[(size_t)step2 * SUB + s];  // capture-layout up, block 0

    float A    = fmaf(s0raw, NL2E, thsynS);   // lane l: accumulator for step == l (mod 64)
    float sA   = fmaf(s1raw, NL2E, thsynS);
    float preA = NL2E * (fmaf(0.5f, up0, 0.5f * thspk) + n0);

    // pipeline fill (zero z-history, so raw reads are exact here)
    float ab0 = hi ? rl(A, 1) : rl(A, 0);
    float xoP = __builtin_amdgcn_rcpf(1.0f + __builtin_amdgcn_exp2f(ab0));
    float abN = hi ? rl(A, 3) : rl(A, 2);   // pair 1; near-corr applied in iter 0
    float pbP = hi ? rl(preA, 1) : rl(preA, 0);

    float xcapH = 0.0f, zcapH = 0.0f;

    float* Yo = out;
    float* Zo = out + 4194304;
    float* Mo = out + 8388608;
    float* Do = out + 12582912;

    for (int B = 0; B < 64; ++B) {
        int t0 = B * 64;
        preLds[l] = preA;                      // this block's pb values
        pbP = hi ? rl(preA, 1) : rl(preA, 0);  // pb pair for steps 0,1

        // prefetch next blocks (consumed at block end; clamped at tail)
        int tP = min(t0 + 128 + l, 4095);
        int tQ = min(t0 + 64 + l, 4095);
        int tU = min(t0 + 64 + step2, 4095);
        float sB   = S_conv[(size_t)tP * SUB + s];
        float upB  = up_mu_Z[(size_t)tQ * SUB + s];
        float nB   = noise[(size_t)tQ * SUB + s];
        float upCn = up_mu_Z[(size_t)tU * SUB + s];

        #pragma unroll
        for (int i = 0; i < 32; ++i) {
            float klo = krow[2 * i];           // taps for z_{2i} scatter
            float khi = krow[2 * i + 1];       // taps for z_{2i+1} scatter
            float pbN = (i < 31) ? preLds[2 * i + 2 + pidx] : 0.0f;

            // second sigmoid for the pair (z for steps 2i, 2i+1)
            float vv = fmaf(xoP, c1, pbP);
            float e2 = __builtin_amdgcn_exp2f(vv);
            float zP = __builtin_amdgcn_rcpf(1.0f + e2);

            // captures (per half); stored directly at block end
            bool cap = (rimC == i);
            xcapH = cap ? xoP : xcapH;
            zcapH = cap ? zP  : zcapH;

            float z0 = rl(zP, 0);              // z_{2i}
            float z1 = rl(zP, 32);             // z_{2i+1}

            // scatter into future accumulators; lanes 2i,2i+1 reset first
            float Ab = (rimR == i) ? sA : A;
            Ab = fmaf(klo, z0, Ab);
            A  = fmaf(khi, z1, Ab);

            // exact cross-pair corrections for steps 2i+2, 2i+3
            abN = fmaf(kca, z0, abN);
            abN = fmaf(kcb, z1, abN);

            // first sigmoid for next pair
            float e1 = __builtin_amdgcn_exp2f(abN);
            xoP = __builtin_amdgcn_rcpf(1.0f + e1);

            // pre-read ab for the pair after next (complete except the
            // correction terms, applied next iter)
            float alo = rl(A, (2 * i + 4) & 63);
            float ahi = rl(A, (2 * i + 5) & 63);
            abN = hi ? ahi : alo;

            pbP = pbN;
        }

        // block end: direct store from capture layout (lane l holds step t0+step2)
        float down = fmaf(xcapH, wspk, thspk);
        float Yv   = xcapH * wsub;
        float mu   = 0.5f * (upC + down);
        size_t o = (size_t)(t0 + step2) * SUB + s;
        Yo[o] = Yv; Zo[o] = zcapH; Mo[o] = mu; Do[o] = down;

        // roll double-buffered inputs
        sA   = fmaf(sB, NL2E, thsynS);
        preA = NL2E * (fmaf(0.5f, upB, 0.5f * thspk) + nB);
        upC  = upCn;
    }
}

extern "C" void kernel_launch(void* const* d_in, const int* in_sizes, int n_in,
                              void* d_out, int out_size, void* d_ws, size_t ws_size,
                              hipStream_t stream) {
    const float* S_conv     = (const float*)d_in[0];
    const float* up_mu_Z    = (const float*)d_in[1];
    const float* noise      = (const float*)d_in[2];
    const float* W_sub      = (const float*)d_in[3];
    const float* theta_syn  = (const float*)d_in[4];
    const float* theta_spike= (const float*)d_in[5];
    const float* W_spike    = (const float*)d_in[6];
    const float* tau_hist   = (const float*)d_in[7];
    const float* K_hist     = (const float*)d_in[8];
    const float* delta_hist = (const float*)d_in[9];
    float* out = (float*)d_out;

    leaf_integ_kernel<<<dim3(1024), dim3(64), 0, stream>>>(
        S_conv, up_mu_Z, noise, W_sub, theta_syn, theta_spike, W_spike,
        tau_hist, K_hist, delta_hist, out);
}